// Round 7
// baseline (15600.560 us; speedup 1.0000x reference)
//
#include <hip/hip_runtime.h>

#define BATCH    16384
#define H_DIM    1024
#define D_DIM    512
#define O_DIM    10
#define SEQ      128
#define BM       128    // rows per block (doubles arithmetic intensity vs r1)
#define NBLK     (BATCH / BM)   // 128 blocks, 1 per CU (128 CUs active by design)
#define NTHREADS 512    // 8 waves, 2/SIMD, 256-VGPR budget
#define HSTR     1040   // i8 h row stride
#define HBUF_SZ  (BM * HSTR)                      // 133120 B, single buffer
#define QW       (127.0f / 0.03125f)
#define QSCALE   (0.03125f / (127.0f * 127.0f))

typedef __bf16 bf16;
typedef __bf16 bf16x8 __attribute__((ext_vector_type(8)));
typedef float  f32x16 __attribute__((ext_vector_type(16)));
typedef float  f32x4  __attribute__((ext_vector_type(4)));
typedef int    i32x4  __attribute__((ext_vector_type(4)));
typedef int    i32x16 __attribute__((ext_vector_type(16)));

__device__ bf16        g_x[BATCH * D_DIM];     // 16 MB
__device__ bf16        g_whx[H_DIM * D_DIM];   // 1 MB (phase-0 only)
__device__ signed char g_whhq[H_DIM * H_DIM];  // 1 MB i8 packed Whh
__device__ bf16        g_wph[O_DIM * H_DIM];   // 20 KB
__device__ bf16        g_xwp[BATCH * H_DIM];   // 32 MB packed xW+bias (NT stream)
__device__ float       g_bias[H_DIM];
__device__ float       g_bph[O_DIM];

__device__ __forceinline__ float fast_tanh(float z) {
  float e = __expf(2.0f * z);
  return 1.0f - 2.0f / (e + 1.0f);
}

__global__ void cvt_bf16(const float* __restrict__ src, bf16* __restrict__ dst, int n) {
  const int i = (blockIdx.x * blockDim.x + threadIdx.x) * 8;
  if (i >= n) return;
  f32x4 s0 = *(const f32x4*)(src + i);
  f32x4 s1 = *(const f32x4*)(src + i + 4);
  bf16x8 v;
  #pragma unroll
  for (int j = 0; j < 4; ++j) { v[j] = (bf16)s0[j]; v[4 + j] = (bf16)s1[j]; }
  *(bf16x8*)(dst + i) = v;
}

// pack Whh -> i8 streams for 8 waves x 2 passes x 32 kc x 2 nt:
// t = (((w*2+p)*32+kc)*2+nt)*64 + lane; encodes
// Whh[w*128 + p*64 + nt*32 + (lane&31)][kc*32 + (lane>>5)*16 + j]
__global__ void pack_whhq(const float* __restrict__ src, signed char* __restrict__ dst) {
  const int t = blockIdx.x * blockDim.x + threadIdx.x;   // 0..65535
  const int lane = t & 63;
  const int nt   = (t >> 6) & 1;
  const int kc   = (t >> 7) & 31;
  const int p    = (t >> 12) & 1;
  const int w    = t >> 13;                              // 0..7
  const int row = w * 128 + p * 64 + nt * 32 + (lane & 31);
  const int col = kc * 32 + (lane >> 5) * 16;
  const float* s = src + (size_t)row * H_DIM + col;
  #pragma unroll
  for (int j = 0; j < 16; ++j) {
    int q = (int)lrintf(s[j] * QW);
    q = q > 127 ? 127 : (q < -127 ? -127 : q);
    dst[(size_t)t * 16 + j] = (signed char)q;
  }
}

__global__ void cvt_bias(const float* __restrict__ bx, const float* __restrict__ bh,
                         const float* __restrict__ bp) {
  const int i = blockIdx.x * blockDim.x + threadIdx.x;
  if (i < H_DIM) g_bias[i] = bx[i] + bh[i];
  if (i < O_DIM) g_bph[i]  = bp[i];
}

// lgkm-only barrier: LDS ops drained, global loads stay in flight
#define LDS_BARRIER()                                      \
  asm volatile("s_waitcnt lgkmcnt(0)" ::: "memory");       \
  __builtin_amdgcn_s_barrier();                            \
  asm volatile("" ::: "memory");

// 128 blocks x 512 threads (8 waves), 1 block/CU, BM=128 rows.
// CHANGE vs r1/r5 (~4600 us, MfmaUtil 20%): DOUBLE ARITHMETIC INTENSITY.
// Each CU's compulsory Whh L2-stream (1 MB/step) now serves 128 batch rows
// instead of 64 -> aggregate Whh L2 traffic halves (16 MB/XCD/step).
// Wave tile 128x128 as two 64-col passes (acc 128 regs, reused per pass);
// pass results deferred in 32 packed-int regs each; single 133 KB LDS h
// buffer; writes only after an all-reads lgkm-barrier (2 barriers/step).
__global__ __launch_bounds__(NTHREADS, 2)
void rnn_fused(float* __restrict__ out)
{
  extern __shared__ char smem[];
  signed char* hbuf = (signed char*)smem;   // h tile, updated in place each step

  const int tid  = threadIdx.x;
  const int wave = tid >> 6;    // 0..7
  const int lane = tid & 63;
  const int m31  = lane & 31;
  const int q    = lane >> 5;
  const int r0   = blockIdx.x * BM;
  const int nw0  = wave * 128;  // this wave's 128-col slice

  const signed char* bstr = g_whhq + (size_t)wave * 131072 + lane * 16;
  bf16* xwbase = g_xwp + (((size_t)blockIdx.x * 8 + wave) * 2) * 8192 + lane * 8;

  i32x4 bq[4][2];   // B-fragment ring (static indices only)

  // ---------------- Phase 0 (bf16): xwb = x @ Whx^T + bias; h1 = q(tanh(xwb)) ----------------
  {
    const bf16* aBase = g_x + (size_t)(r0 + m31) * D_DIM + q * 8;
    #pragma unroll
    for (int p = 0; p < 2; ++p) {
      f32x16 accf[4][2];
      #pragma unroll
      for (int mt = 0; mt < 4; ++mt)
        #pragma unroll
        for (int nt = 0; nt < 2; ++nt)
          #pragma unroll
          for (int i = 0; i < 16; ++i) accf[mt][nt][i] = 0.0f;

      const int cb = nw0 + p * 64;
      #pragma unroll 2
      for (int kc = 0; kc < D_DIM / 16; ++kc) {
        bf16x8 a[4], b[2];
        #pragma unroll
        for (int mt = 0; mt < 4; ++mt)
          a[mt] = *(const bf16x8*)(aBase + (size_t)mt * 32 * D_DIM + kc * 16);
        #pragma unroll
        for (int nt = 0; nt < 2; ++nt)
          b[nt] = *(const bf16x8*)(g_whx + (size_t)(cb + nt * 32 + m31) * D_DIM + kc * 16 + q * 8);
        #pragma unroll
        for (int mt = 0; mt < 4; ++mt)
          #pragma unroll
          for (int nt = 0; nt < 2; ++nt)
            accf[mt][nt] = __builtin_amdgcn_mfma_f32_32x32x16_bf16(a[mt], b[nt], accf[mt][nt], 0, 0, 0);
      }

      bf16* xb = xwbase + p * 8192;
      #pragma unroll
      for (int f = 0; f < 8; ++f) {
        const int mt = f >> 1, nt = f & 1;
        const int col = cb + nt * 32 + m31;
        const float bias = g_bias[col];
        bf16x8 lo, hi;
        #pragma unroll
        for (int r = 0; r < 16; ++r) {
          const int row = mt * 32 + (r & 3) + 8 * (r >> 2) + 4 * q;  // C/D layout (m74/m101)
          const float v = accf[mt][nt][r] + bias;
          if (r < 8) lo[r] = (bf16)v; else hi[r - 8] = (bf16)v;
          hbuf[row * HSTR + col] = (signed char)__float2int_rn(fast_tanh(v) * 127.0f);
        }
        __builtin_nontemporal_store(lo, (bf16x8*)(xb + (f * 2) * 512));
        __builtin_nontemporal_store(hi, (bf16x8*)(xb + (f * 2 + 1) * 512));
      }
    }
  }

  // NT stores must retire before steps reload them (barriers don't drain vmcnt)
  asm volatile("s_waitcnt vmcnt(0)" ::: "memory");

  // ring-warm for step-1 pass-0
  #pragma unroll
  for (int pp = 0; pp < 4; ++pp)
    #pragma unroll
    for (int nt = 0; nt < 2; ++nt)
      bq[pp][nt] = *(const i32x4*)(bstr + (pp * 2 + nt) * 1024);

  LDS_BARRIER()

  // ---------------- RNN steps 2..SEQ (i8 MFMA, K=32, 2 col-passes, 2 barriers/step) ---------
  const signed char* aB[4];
  #pragma unroll
  for (int mt = 0; mt < 4; ++mt)
    aB[mt] = hbuf + (mt * 32 + m31) * HSTR + q * 16;

  for (int step = 1; step < SEQ; ++step) {
    int pA_[32], pB_[32];   // deferred quantized h (4 bytes/int), static-indexed

    #pragma unroll
    for (int p = 0; p < 2; ++p) {
      i32x16 acc[4][2];
      #pragma unroll
      for (int mt = 0; mt < 4; ++mt)
        #pragma unroll
        for (int nt = 0; nt < 2; ++nt)
          #pragma unroll
          for (int i = 0; i < 16; ++i) acc[mt][nt][i] = 0;

      const signed char* bp = bstr + p * 65536;

      __builtin_amdgcn_s_setprio(1);
      #pragma unroll
      for (int kc = 0; kc < 32; ++kc) {
        i32x4 a0 = *(const i32x4*)(aB[0] + kc * 32);
        i32x4 a1 = *(const i32x4*)(aB[1] + kc * 32);
        i32x4 a2 = *(const i32x4*)(aB[2] + kc * 32);
        i32x4 a3 = *(const i32x4*)(aB[3] + kc * 32);
        #pragma unroll
        for (int nt = 0; nt < 2; ++nt) {
          acc[0][nt] = __builtin_amdgcn_mfma_i32_32x32x32_i8(a0, bq[kc & 3][nt], acc[0][nt], 0, 0, 0);
          acc[1][nt] = __builtin_amdgcn_mfma_i32_32x32x32_i8(a1, bq[kc & 3][nt], acc[1][nt], 0, 0, 0);
          acc[2][nt] = __builtin_amdgcn_mfma_i32_32x32x32_i8(a2, bq[kc & 3][nt], acc[2][nt], 0, 0, 0);
          acc[3][nt] = __builtin_amdgcn_mfma_i32_32x32x32_i8(a3, bq[kc & 3][nt], acc[3][nt], 0, 0, 0);
        }
        if (kc < 28) {
          #pragma unroll
          for (int nt = 0; nt < 2; ++nt)
            bq[kc & 3][nt] = *(const i32x4*)(bp + ((kc + 4) * 2 + nt) * 1024);
        }
      }
      __builtin_amdgcn_s_setprio(0);

      // ---- pass epilogue: xq chunks (prefetch-2) + tanh/quantize into packed regs ----
      const bf16* xb = xwbase + p * 8192;
      bf16x8 xl[2], xh[2];
      xl[0] = __builtin_nontemporal_load((const bf16x8*)(xb + 0 * 512));
      xh[0] = __builtin_nontemporal_load((const bf16x8*)(xb + 1 * 512));
      xl[1] = __builtin_nontemporal_load((const bf16x8*)(xb + 2 * 512));
      xh[1] = __builtin_nontemporal_load((const bf16x8*)(xb + 3 * 512));

      // ring-warm for next pass (p=0 -> pass1; p=1 -> next step's pass0)
      const signed char* bpn = (p == 0) ? (bstr + 65536) : bstr;
      #pragma unroll
      for (int pp = 0; pp < 4; ++pp)
        #pragma unroll
        for (int nt = 0; nt < 2; ++nt)
          bq[pp][nt] = *(const i32x4*)(bpn + (pp * 2 + nt) * 1024);

      #pragma unroll
      for (int f = 0; f < 8; ++f) {
        const int mt = f >> 1, nt = f & 1;
        int w0 = 0, w1 = 0, w2 = 0, w3 = 0;
        #pragma unroll
        for (int r = 0; r < 16; ++r) {
          const float xv = (float)((r < 8) ? xl[f & 1][r] : xh[f & 1][r - 8]);
          const float v  = (float)acc[mt][nt][r] * QSCALE + xv;
          const int   q8 = (int)__float2int_rn(fast_tanh(v) * 127.0f) & 255;
          const int   sh = (r & 3) * 8;
          if ((r >> 2) == 0) w0 |= q8 << sh;
          else if ((r >> 2) == 1) w1 |= q8 << sh;
          else if ((r >> 2) == 2) w2 |= q8 << sh;
          else w3 |= q8 << sh;
        }
        if (p == 0) { pA_[f * 4] = w0; pA_[f * 4 + 1] = w1; pA_[f * 4 + 2] = w2; pA_[f * 4 + 3] = w3; }
        else        { pB_[f * 4] = w0; pB_[f * 4 + 1] = w1; pB_[f * 4 + 2] = w2; pB_[f * 4 + 3] = w3; }
        if (f < 6) {
          xl[f & 1] = __builtin_nontemporal_load((const bf16x8*)(xb + ((f + 2) * 2) * 512));
          xh[f & 1] = __builtin_nontemporal_load((const bf16x8*)(xb + ((f + 2) * 2 + 1) * 512));
        }
      }
    }

    LDS_BARRIER()   // all waves done READING h_t (epilogues touch no LDS)

    // ---- write h_{t+1} in place from packed regs ----
    #pragma unroll
    for (int p = 0; p < 2; ++p) {
      #pragma unroll
      for (int f = 0; f < 8; ++f) {
        const int mt = f >> 1, nt = f & 1;
        const int col = nw0 + p * 64 + nt * 32 + m31;
        #pragma unroll
        for (int jj = 0; jj < 4; ++jj) {
          const int pk = (p == 0) ? pA_[f * 4 + jj] : pB_[f * 4 + jj];
          #pragma unroll
          for (int b = 0; b < 4; ++b) {
            const int row = mt * 32 + b + 8 * jj + 4 * q;
            hbuf[row * HSTR + col] = (signed char)(pk >> (b * 8));
          }
        }
      }
    }

    LDS_BARRIER()   // h_{t+1} visible
  }

  // ---------------- Output head: softmax(h @ Wph^T + b), fp32 out ----------------
  {
    const int row  = tid >> 2;   // 0..127
    const int tsub = tid & 3;    // 4 threads per row, 256 k each
    float p[O_DIM];
    #pragma unroll
    for (int o = 0; o < O_DIM; ++o) p[o] = 0.0f;

    const signed char* hrow = hbuf + row * HSTR + tsub * 256;
    for (int kk = 0; kk < 256; kk += 16) {
      i32x4 hp = *(const i32x4*)(hrow + kk);
      float hf[16];
      #pragma unroll
      for (int d = 0; d < 4; ++d)
        #pragma unroll
        for (int j = 0; j < 4; ++j)
          hf[d * 4 + j] = (float)((int)(hp[d] << ((3 - j) * 8)) >> 24);
      #pragma unroll
      for (int o = 0; o < O_DIM; ++o) {
        bf16x8 wv0 = *(const bf16x8*)(g_wph + (size_t)o * H_DIM + tsub * 256 + kk);
        bf16x8 wv1 = *(const bf16x8*)(g_wph + (size_t)o * H_DIM + tsub * 256 + kk + 8);
        #pragma unroll
        for (int j = 0; j < 8; ++j) {
          p[o] += hf[j] * (float)wv0[j];
          p[o] += hf[8 + j] * (float)wv1[j];
        }
      }
    }
    #pragma unroll
    for (int d = 1; d < 4; d <<= 1)
      #pragma unroll
      for (int o = 0; o < O_DIM; ++o) p[o] += __shfl_xor(p[o], d, 4);

    if (tsub == 0) {
      float v[O_DIM], mx = -1e30f;
      #pragma unroll
      for (int o = 0; o < O_DIM; ++o) {
        v[o] = p[o] * (1.0f / 127.0f) + g_bph[o];
        mx = fmaxf(mx, v[o]);
      }
      float s = 0.0f;
      #pragma unroll
      for (int o = 0; o < O_DIM; ++o) { v[o] = __expf(v[o] - mx); s += v[o]; }
      const float inv = 1.0f / s;
      #pragma unroll
      for (int o = 0; o < O_DIM; ++o)
        out[(size_t)(r0 + row) * O_DIM + o] = v[o] * inv;
    }
  }
}

extern "C" void kernel_launch(void* const* d_in, const int* in_sizes, int n_in,
                              void* d_out, int out_size, void* d_ws, size_t ws_size,
                              hipStream_t stream)
{
  (void)d_ws; (void)ws_size; (void)in_sizes; (void)n_in; (void)out_size;
  const float* x     = (const float*)d_in[0];
  const float* Whx_w = (const float*)d_in[1];
  const float* Whx_b = (const float*)d_in[2];
  const float* Whh_w = (const float*)d_in[3];
  const float* Whh_b = (const float*)d_in[4];
  const float* Wph_w = (const float*)d_in[5];
  const float* Wph_b = (const float*)d_in[6];
  float* out = (float*)d_out;

  (void)hipFuncSetAttribute((const void*)rnn_fused,
                            hipFuncAttributeMaxDynamicSharedMemorySize, HBUF_SZ);

  bf16* gx; bf16* gwhx; signed char* gwhhq; bf16* gwph;
  hipGetSymbolAddress((void**)&gx,    HIP_SYMBOL(g_x));
  hipGetSymbolAddress((void**)&gwhx,  HIP_SYMBOL(g_whx));
  hipGetSymbolAddress((void**)&gwhhq, HIP_SYMBOL(g_whhq));
  hipGetSymbolAddress((void**)&gwph,  HIP_SYMBOL(g_wph));

  cvt_bf16<<<BATCH * D_DIM / 2048, 256, 0, stream>>>(x,     gx,   BATCH * D_DIM);
  cvt_bf16<<<H_DIM * D_DIM / 2048, 256, 0, stream>>>(Whx_w, gwhx, H_DIM * D_DIM);
  pack_whhq<<<65536 / 256, 256, 0, stream>>>(Whh_w, gwhhq);
  cvt_bf16<<<(O_DIM * H_DIM / 8 + 255) / 256, 256, 0, stream>>>(Wph_w, gwph, O_DIM * H_DIM);
  cvt_bias<<<4, 256, 0, stream>>>(Whx_b, Whh_b, Wph_b);

  // 128 blocks x 512 thr, 1 block/CU
  const dim3 grid(NBLK), block(NTHREADS);
  rnn_fused<<<grid, block, HBUF_SZ, stream>>>(out);
}

// Round 8
// 4986.007 us; speedup vs baseline: 3.1289x; 3.1289x over previous
//
#include <hip/hip_runtime.h>

#define BATCH    16384
#define H_DIM    1024
#define D_DIM    512
#define O_DIM    10
#define SEQ      128
#define BM       64
#define NTHREADS 1024   // 16 waves/block, 1 block/CU
#define HSTR     1040   // i8 h row stride (16-B aligned; 4-bank offset -> low-conflict b128)
#define HBUF_SZ  (BM * HSTR)                      // 66560 B (single h buffer, in-place update)
#define BSTG_OFF HBUF_SZ                          // per-wave B staging region starts here
#define LDS_TOT  (HBUF_SZ + 16 * 4096)            // 66560 + 65536 = 132096 B
#define QW       (127.0f / 0.03125f)              // weight quant scale (bound = 1/sqrt(1024))
#define QSCALE   (0.03125f / (127.0f * 127.0f))   // dequant: acc_i32 -> float

#define AS1 __attribute__((address_space(1)))
#define AS3 __attribute__((address_space(3)))

typedef __bf16 bf16;
typedef __bf16 bf16x8 __attribute__((ext_vector_type(8)));
typedef float  f32x16 __attribute__((ext_vector_type(16)));
typedef float  f32x4  __attribute__((ext_vector_type(4)));
typedef int    i32x4  __attribute__((ext_vector_type(4)));
typedef int    i32x16 __attribute__((ext_vector_type(16)));

// ---- static device buffers ----
__device__ bf16        g_x[BATCH * D_DIM];     // 16 MB
__device__ bf16        g_whx[H_DIM * D_DIM];   // 1 MB (phase-0 only)
__device__ signed char g_whhq[H_DIM * H_DIM];  // 1 MB i8 wave-fragment-packed Whh
__device__ bf16        g_wph[O_DIM * H_DIM];   // 20 KB
__device__ bf16        g_xwp[BATCH * H_DIM];   // 32 MB packed xW+bias (NT stream)
__device__ float       g_bias[H_DIM];
__device__ float       g_bph[O_DIM];

__device__ __forceinline__ float fast_tanh(float z) {
  float e = __expf(2.0f * z);
  return 1.0f - 2.0f / (e + 1.0f);
}

__global__ void cvt_bf16(const float* __restrict__ src, bf16* __restrict__ dst, int n) {
  const int i = (blockIdx.x * blockDim.x + threadIdx.x) * 8;
  if (i >= n) return;
  f32x4 s0 = *(const f32x4*)(src + i);
  f32x4 s1 = *(const f32x4*)(src + i + 4);
  bf16x8 v;
  #pragma unroll
  for (int j = 0; j < 4; ++j) { v[j] = (bf16)s0[j]; v[4 + j] = (bf16)s1[j]; }
  *(bf16x8*)(dst + i) = v;
}

// pack Whh -> i8 per-wave streams for 16 waves x 2 n-frags x K=32 MFMA:
// byte addr = w*65536 + kc*2048 + nt*1024 + lane*16  (lane-contiguous per (kc,nt):
// exactly the global_load_lds write order base+lane*16).
__global__ void pack_whhq(const float* __restrict__ src, signed char* __restrict__ dst) {
  const int t = blockIdx.x * blockDim.x + threadIdx.x;   // 0..65535
  const int lane = t & 63;
  const int nt   = (t >> 6) & 1;
  const int kc   = (t >> 7) & 31;
  const int w    = t >> 12;
  const int row = w * 64 + nt * 32 + (lane & 31);
  const int col = kc * 32 + (lane >> 5) * 16;
  const float* s = src + (size_t)row * H_DIM + col;
  #pragma unroll
  for (int j = 0; j < 16; ++j) {
    int q = (int)lrintf(s[j] * QW);
    q = q > 127 ? 127 : (q < -127 ? -127 : q);
    dst[(size_t)t * 16 + j] = (signed char)q;
  }
}

__global__ void cvt_bias(const float* __restrict__ bx, const float* __restrict__ bh,
                         const float* __restrict__ bp) {
  const int i = blockIdx.x * blockDim.x + threadIdx.x;
  if (i < H_DIM) g_bias[i] = bx[i] + bh[i];
  if (i < O_DIM) g_bph[i]  = bp[i];
}

#define MFMA4_BF16(A0, A1, B)                                                            \
  accf[0][0] = __builtin_amdgcn_mfma_f32_32x32x16_bf16(A0, (B)[0], accf[0][0], 0, 0, 0); \
  accf[0][1] = __builtin_amdgcn_mfma_f32_32x32x16_bf16(A0, (B)[1], accf[0][1], 0, 0, 0); \
  accf[1][0] = __builtin_amdgcn_mfma_f32_32x32x16_bf16(A1, (B)[0], accf[1][0], 0, 0, 0); \
  accf[1][1] = __builtin_amdgcn_mfma_f32_32x32x16_bf16(A1, (B)[1], accf[1][1], 0, 0, 0);

// raw barrier: LDS ops drained (lgkmcnt(0)); global/DMA loads stay IN FLIGHT across it.
#define LDS_BARRIER()                                      \
  asm volatile("s_waitcnt lgkmcnt(0)" ::: "memory");       \
  __builtin_amdgcn_s_barrier();                            \
  asm volatile("" ::: "memory");

// 256 blocks x 1024 threads, 1 block/CU, wave tile 64x64 -- r1's proven decomposition.
// CHANGE vs r5 (4615 us, MfmaUtil 20%): B-stream moved from a depth-4 VGPR ring
// (8 KB/wave in flight -> Little's-law-capped at ~13 B/cyc/CU, the measured wall)
// to global_load_lds double-buffered per-wave private LDS (2 KB/kc). DMA loads
// occupy no VGPRs and no per-lane issue; 16 waves x 2 staged batches keep
// 32-64 KB/CU outstanding -> B delivery no longer latency-bound. Counted
// vmcnt(2) per kc (never drained); stage issued AFTER the kc's MFMAs so the
// destination buffer's ds_reads are provably retired (operand lgkm-waits).
// xq NT loads issued at kc=29 (latency hidden under kc 30..31 + drain).
__global__ __launch_bounds__(NTHREADS, 3)
void rnn_fused(float* __restrict__ out)
{
  extern __shared__ char smem[];
  signed char* hbuf = (signed char*)smem;            // h tile, updated in place

  const int tid  = threadIdx.x;
  const int wave = tid >> 6;    // 0..15
  const int lane = tid & 63;
  const int m31  = lane & 31;
  const int q    = lane >> 5;
  const int r0   = blockIdx.x * BM;
  const int nw0  = wave * 64;   // this wave's 64-col slice

  const signed char* bsrc = g_whhq + (size_t)wave * 65536 + lane * 16;  // per-lane global src
  char* myB  = smem + BSTG_OFF + wave * 4096;                 // wave-uniform LDS dst base
  const signed char* myBr = (const signed char*)myB + lane * 16;  // per-lane LDS read addr
  bf16* xbase = g_xwp + ((size_t)blockIdx.x * 16 + wave) * 4096 + lane * 8;

  // stage one kc (2 KB: nt=0,1) into buffer (KT&1); HW writes lane i at dst+16*i
  #define STAGE(KT)                                                                        \
    __builtin_amdgcn_global_load_lds((const AS1 void*)(bsrc + (KT) * 2048),                \
                                     (AS3 void*)(myB + ((KT) & 1) * 2048), 16, 0, 0);      \
    __builtin_amdgcn_global_load_lds((const AS1 void*)(bsrc + (KT) * 2048 + 1024),         \
                                     (AS3 void*)(myB + ((KT) & 1) * 2048 + 1024), 16, 0, 0);

  // ---------------- Phase 0 (bf16): xwb = x @ Whx^T + bias; h1 = q(tanh(xwb)) ----------------
  {
    f32x16 accf[2][2];
    #pragma unroll
    for (int mt = 0; mt < 2; ++mt)
      #pragma unroll
      for (int nt = 0; nt < 2; ++nt)
        #pragma unroll
        for (int i = 0; i < 16; ++i) accf[mt][nt][i] = 0.0f;

    const bf16* aBase = g_x + (size_t)(r0 + m31) * D_DIM + q * 8;
    #pragma unroll 4
    for (int kc = 0; kc < D_DIM / 16; ++kc) {
      bf16x8 a0 = *(const bf16x8*)(aBase + kc * 16);
      bf16x8 a1 = *(const bf16x8*)(aBase + (size_t)32 * D_DIM + kc * 16);
      bf16x8 b[2];
      #pragma unroll
      for (int nt = 0; nt < 2; ++nt)
        b[nt] = *(const bf16x8*)(g_whx + (size_t)(nw0 + nt * 32 + m31) * D_DIM + kc * 16 + q * 8);
      MFMA4_BF16(a0, a1, b);
    }

    bf16x8 xq0[8];
    #pragma unroll
    for (int nt = 0; nt < 2; ++nt) {
      const int col = nw0 + nt * 32 + m31;
      const float bias = g_bias[col];
      #pragma unroll
      for (int mt = 0; mt < 2; ++mt)
        #pragma unroll
        for (int r = 0; r < 16; ++r) {
          const int row = mt * 32 + (r & 3) + 8 * (r >> 2) + 4 * q;  // C/D layout (m74/m101)
          const int idx = (nt * 2 + mt) * 16 + r;
          const float v = accf[mt][nt][r] + bias;
          xq0[idx >> 3][idx & 7] = (bf16)v;
          hbuf[row * HSTR + col] = (signed char)__float2int_rn(fast_tanh(v) * 127.0f);
        }
    }
    #pragma unroll
    for (int i = 0; i < 8; ++i)
      __builtin_nontemporal_store(xq0[i], (bf16x8*)(xbase + i * 512));
  }

  // NT stores retired before reload; also clears the vmcnt queue for counted waits
  asm volatile("s_waitcnt vmcnt(0)" ::: "memory");

  // prologue stage: kc=0 -> buf0, kc=1 -> buf1 (fly across the barrier)
  STAGE(0)
  STAGE(1)

  LDS_BARRIER()

  // ---------------- RNN steps 2..SEQ (i8 MFMA, K=32) ----------------
  const signed char* aP0 = hbuf + m31 * HSTR + q * 16;
  const signed char* aP1 = aP0 + 32 * HSTR;

  for (int step = 1; step < SEQ; ++step) {
    i32x16 acc[2][2];
    #pragma unroll
    for (int mt = 0; mt < 2; ++mt)
      #pragma unroll
      for (int nt = 0; nt < 2; ++nt)
        #pragma unroll
        for (int i = 0; i < 16; ++i) acc[mt][nt][i] = 0;

    bf16x8 xq[8];   // loaded at kc==29, consumed in epilogue

    __builtin_amdgcn_s_setprio(1);
    #pragma unroll
    for (int kc = 0; kc < 32; ++kc) {
      // counted wait: guarantees stage(kc) landed; keeps newer stages (and xq) in flight
      if (kc < 30) { asm volatile("s_waitcnt vmcnt(2)" ::: "memory"); }
      else         { asm volatile("s_waitcnt vmcnt(10)" ::: "memory"); }

      i32x4 b0 = *(const i32x4*)(myBr + (kc & 1) * 2048);
      i32x4 b1 = *(const i32x4*)(myBr + (kc & 1) * 2048 + 1024);
      i32x4 a0 = *(const i32x4*)(aP0 + kc * 32);
      i32x4 a1 = *(const i32x4*)(aP1 + kc * 32);
      acc[0][0] = __builtin_amdgcn_mfma_i32_32x32x32_i8(a0, b0, acc[0][0], 0, 0, 0);
      acc[0][1] = __builtin_amdgcn_mfma_i32_32x32x32_i8(a0, b1, acc[0][1], 0, 0, 0);
      acc[1][0] = __builtin_amdgcn_mfma_i32_32x32x32_i8(a1, b0, acc[1][0], 0, 0, 0);
      acc[1][1] = __builtin_amdgcn_mfma_i32_32x32x32_i8(a1, b1, acc[1][1], 0, 0, 0);

      // stage kc+2 AFTER this kc's MFMAs: operand lgkm-waits ensured the target
      // buffer's ds_reads retired, so the DMA overwrite is safe. (kc+2)&31 wraps
      // to the NEXT step's kc 0/1 -- addresses are step-invariant.
      __builtin_amdgcn_sched_barrier(0);
      STAGE((kc + 2) & 31)

      if (kc == 29) {
        #pragma unroll
        for (int i = 0; i < 8; ++i)
          xq[i] = __builtin_nontemporal_load((const bf16x8*)(xbase + i * 512));
      }
    }
    __builtin_amdgcn_s_setprio(0);

    // xq retired; next-step stages (ns0,ns1) remain in flight across both barriers
    asm volatile("s_waitcnt vmcnt(4)" ::: "memory");

    LDS_BARRIER()   // all waves done READING hbuf

    #pragma unroll
    for (int nt = 0; nt < 2; ++nt) {
      const int col = nw0 + nt * 32 + m31;
      #pragma unroll
      for (int mt = 0; mt < 2; ++mt)
        #pragma unroll
        for (int r = 0; r < 16; ++r) {
          const int row = mt * 32 + (r & 3) + 8 * (r >> 2) + 4 * q;
          const int idx = (nt * 2 + mt) * 16 + r;
          const float v = (float)acc[mt][nt][r] * QSCALE + (float)xq[idx >> 3][idx & 7];
          hbuf[row * HSTR + col] = (signed char)__float2int_rn(fast_tanh(v) * 127.0f);
        }
    }

    LDS_BARRIER()   // new h visible
  }

  // ---------------- Output head: softmax(h @ Wph^T + b), fp32 out ----------------
  {
    const int row  = tid >> 4;   // 0..63
    const int tsub = tid & 15;   // 16 threads per row, k-partitioned
    float p[O_DIM];
    #pragma unroll
    for (int o = 0; o < O_DIM; ++o) p[o] = 0.0f;

    const signed char* hrow = hbuf + row * HSTR + tsub * 64;
    for (int kk = 0; kk < 64; kk += 16) {
      i32x4 hp = *(const i32x4*)(hrow + kk);
      float hf[16];
      #pragma unroll
      for (int d = 0; d < 4; ++d)
        #pragma unroll
        for (int j = 0; j < 4; ++j)
          hf[d * 4 + j] = (float)((int)(hp[d] << ((3 - j) * 8)) >> 24);
      #pragma unroll
      for (int o = 0; o < O_DIM; ++o) {
        bf16x8 wv0 = *(const bf16x8*)(g_wph + (size_t)o * H_DIM + tsub * 64 + kk);
        bf16x8 wv1 = *(const bf16x8*)(g_wph + (size_t)o * H_DIM + tsub * 64 + kk + 8);
        #pragma unroll
        for (int j = 0; j < 8; ++j) {
          p[o] += hf[j] * (float)wv0[j];
          p[o] += hf[8 + j] * (float)wv1[j];
        }
      }
    }
    #pragma unroll
    for (int d = 1; d < 16; d <<= 1)
      #pragma unroll
      for (int o = 0; o < O_DIM; ++o) p[o] += __shfl_xor(p[o], d, 16);

    if (tsub == 0) {
      float v[O_DIM], mx = -1e30f;
      #pragma unroll
      for (int o = 0; o < O_DIM; ++o) {
        v[o] = p[o] * (1.0f / 127.0f) + g_bph[o];
        mx = fmaxf(mx, v[o]);
      }
      float s = 0.0f;
      #pragma unroll
      for (int o = 0; o < O_DIM; ++o) { v[o] = __expf(v[o] - mx); s += v[o]; }
      const float inv = 1.0f / s;
      #pragma unroll
      for (int o = 0; o < O_DIM; ++o)
        out[(size_t)(r0 + row) * O_DIM + o] = v[o] * inv;
    }
  }
}

extern "C" void kernel_launch(void* const* d_in, const int* in_sizes, int n_in,
                              void* d_out, int out_size, void* d_ws, size_t ws_size,
                              hipStream_t stream)
{
  (void)d_ws; (void)ws_size; (void)in_sizes; (void)n_in; (void)out_size;
  const float* x     = (const float*)d_in[0];
  const float* Whx_w = (const float*)d_in[1];
  const float* Whx_b = (const float*)d_in[2];
  const float* Whh_w = (const float*)d_in[3];
  const float* Whh_b = (const float*)d_in[4];
  const float* Wph_w = (const float*)d_in[5];
  const float* Wph_b = (const float*)d_in[6];
  float* out = (float*)d_out;

  (void)hipFuncSetAttribute((const void*)rnn_fused,
                            hipFuncAttributeMaxDynamicSharedMemorySize, LDS_TOT);

  bf16* gx; bf16* gwhx; signed char* gwhhq; bf16* gwph;
  hipGetSymbolAddress((void**)&gx,    HIP_SYMBOL(g_x));
  hipGetSymbolAddress((void**)&gwhx,  HIP_SYMBOL(g_whx));
  hipGetSymbolAddress((void**)&gwhhq, HIP_SYMBOL(g_whhq));
  hipGetSymbolAddress((void**)&gwph,  HIP_SYMBOL(g_wph));

  cvt_bf16<<<BATCH * D_DIM / 2048, 256, 0, stream>>>(x,     gx,   BATCH * D_DIM);
  cvt_bf16<<<H_DIM * D_DIM / 2048, 256, 0, stream>>>(Whx_w, gwhx, H_DIM * D_DIM);
  pack_whhq<<<65536 / 256, 256, 0, stream>>>(Whh_w, gwhhq);
  cvt_bf16<<<(O_DIM * H_DIM / 8 + 255) / 256, 256, 0, stream>>>(Wph_w, gwph, O_DIM * H_DIM);
  cvt_bias<<<4, 256, 0, stream>>>(Whx_b, Whh_b, Wph_b);

  // 256 blocks x 1024 thr, 1 block/CU
  const dim3 grid(BATCH / BM), block(NTHREADS);
  rnn_fused<<<grid, block, LDS_TOT, stream>>>(out);
}